// Round 14
// baseline (280.628 us; speedup 1.0000x reference)
//
#include <hip/hip_runtime.h>

// SVGP-KAN POD moment-matching:
//   mean[b,g] = sum_l a_mu[b,l] * p_mu[g,l]
//   var[b,g]  = sum_l a_var*(pm^2+pv) + a_mu^2 * pv
// B=2048, G=16384, L=16. Output = 268 MB streaming writes (~42 us at 6.4 TB/s).
//
// Ledger: R6 NT-stores 333us -> R8 plain stores 324us (NT exonerated)
//         -> R10 LDS operand staging 276us (~70us kernel, 3.8 TB/s: vmcnt
//         load/store coupling confirmed as the R8 limiter).
// R11 theory: 12x ds_read_b128/iter per wave = 2304 LDS-cyc per 16KB stored
// vs 1575-cyc store drain -> LDS return path bound at ~4.4 TB/s.
// Fix: RG 2->4 (2x stored bytes per iter, same broadcast reads) and drop the
// s_am2 array (compute am^2 and q1=pm^2+pv in registers) -> 8 ds_read/iter.
// New LDS budget 768 cyc < 1575 drain -> store-bound.

constexpr int L   = 16;   // reduction length (fixed by problem)
constexpr int RG  = 4;    // g-columns per thread -> float4 stores (16B/lane)
constexpr int BT  = 64;   // b-rows per block
constexpr int TPB = 256;  // threads per block

typedef float v4f __attribute__((ext_vector_type(4)));

__global__ __launch_bounds__(TPB) void svgp_pod_kernel(
    const float* __restrict__ a_mu, const float* __restrict__ a_var,
    const float* __restrict__ p_mu, const float* __restrict__ p_var,
    float* __restrict__ out_mean, float* __restrict__ out_var,
    int B, int G)
{
    __shared__ v4f s_am[BT][L / 4];   // a_mu rows   (4 KB)
    __shared__ v4f s_av[BT][L / 4];   // a_var rows  (4 KB)

    const int tid = threadIdx.x;
    const int g0  = (blockIdx.x * TPB + tid) * RG;
    const int b0  = blockIdx.y * BT;

    // ---- cooperative a-row staging: 256 thr x 16B = 4KB contiguous per array ----
    {
        const int r = tid >> 2;          // 0..63  (b-row within tile)
        const int c = tid & 3;           // 0..3   (float4 chunk within row)
        const long long base = (long long)(b0 + r) * L + c * 4;
        s_am[r][c] = *reinterpret_cast<const v4f*>(a_mu + base);
        s_av[r][c] = *reinterpret_cast<const v4f*>(a_var + base);
    }

    // ---- per-thread g-side fragments: v4f across the RG quad (128 VGPR) ----
    // pmv[l][r] = p_mu[g0+r][l]  (transpose of 4 contiguous rows)
    v4f pmv[L], pvv[L];
#pragma unroll
    for (int r = 0; r < RG; ++r) {
        const v4f* pm4 = reinterpret_cast<const v4f*>(p_mu + (long long)(g0 + r) * L);
        const v4f* pv4 = reinterpret_cast<const v4f*>(p_var + (long long)(g0 + r) * L);
#pragma unroll
        for (int c = 0; c < L / 4; ++c) {
            v4f m = pm4[c], v = pv4[c];
            pmv[4*c+0][r] = m.x; pmv[4*c+1][r] = m.y;
            pmv[4*c+2][r] = m.z; pmv[4*c+3][r] = m.w;
            pvv[4*c+0][r] = v.x; pvv[4*c+1][r] = v.y;
            pvv[4*c+2][r] = v.z; pvv[4*c+3][r] = v.w;
        }
    }

    __syncthreads();

    // ---- b-loop: 8 broadcast ds_reads/iter, q1 & am^2 recomputed in-reg ----
#pragma unroll 2
    for (int i = 0; i < BT; ++i) {
        v4f mean = {0.f, 0.f, 0.f, 0.f};
        v4f var  = {0.f, 0.f, 0.f, 0.f};
#pragma unroll
        for (int c = 0; c < L / 4; ++c) {
            const v4f am  = s_am[i][c];
            const v4f av  = s_av[i][c];
            const v4f am2 = am * am;
#define POD_STEP(J)                                                    \
            {                                                          \
                const int l = 4 * c + (J);                             \
                const v4f q1   = pmv[l] * pmv[l] + pvv[l];             \
                const v4f amv  = {am[J],  am[J],  am[J],  am[J]};      \
                const v4f am2v = {am2[J], am2[J], am2[J], am2[J]};     \
                const v4f avv  = {av[J],  av[J],  av[J],  av[J]};      \
                mean = amv  * pmv[l] + mean;                           \
                var  = avv  * q1     + var;                            \
                var  = am2v * pvv[l] + var;                            \
            }
            POD_STEP(0) POD_STEP(1) POD_STEP(2) POD_STEP(3)
#undef POD_STEP
        }

        // 32-bit offset: max = 2048*16384 = 33.5M << 2^31; g0%4==0 -> 16B aligned
        const int off = (b0 + i) * G + g0;
        *reinterpret_cast<v4f*>(out_mean + off) = mean;
        *reinterpret_cast<v4f*>(out_var  + off) = var;
    }
}

extern "C" void kernel_launch(void* const* d_in, const int* in_sizes, int n_in,
                              void* d_out, int out_size, void* d_ws, size_t ws_size,
                              hipStream_t stream) {
    const float* a_mu  = (const float*)d_in[0];
    const float* a_var = (const float*)d_in[1];
    const float* p_mu  = (const float*)d_in[2];
    const float* p_var = (const float*)d_in[3];

    const int B = in_sizes[0] / L;      // 2048
    const int G = in_sizes[2] / L;      // 16384

    float* out_mean = (float*)d_out;
    float* out_var  = out_mean + (long long)B * G;

    dim3 grid((unsigned)(G / (TPB * RG)), (unsigned)(B / BT));  // 16 x 32 = 512 blocks
    svgp_pod_kernel<<<grid, TPB, 0, stream>>>(a_mu, a_var, p_mu, p_var,
                                              out_mean, out_var, B, G);
}